// Round 1
// baseline (305.062 us; speedup 1.0000x reference)
//
#include <hip/hip_runtime.h>
#include <stdint.h>

#define NB 1024
#define BB 256
#define KK 16
#define HH 64
#define WW 64
#define F_FULL 144   // 9*K
#define HDIM 128
#define CDIM 16

// ---------------- ws layout ----------------
// [0,4)                      : int err_count
// [256, 256+16*144*128*4)    : W1v (16 shifted variants of W1, fp32)
// [256+1179648, +16777216)   : zt  u8, layout (H,W,B,K)
#define W1V_OFF 256
#define W1V_BYTES (16 * F_FULL * HDIM * 4)
#define ZT_OFF (W1V_OFF + W1V_BYTES)

// Build the 16 drop-shifted weight variants:
// W1v[s][g][h] = 0 if g==64+s ; W1[g - (g>64+s)][h] otherwise
__global__ void build_w1v(const float* __restrict__ W1, float* __restrict__ W1v) {
    int idx = blockIdx.x * 256 + threadIdx.x;   // 16*144*128 = 294912 total
    if (idx >= 16 * F_FULL * HDIM) return;
    int h = idx % HDIM;
    int g = (idx / HDIM) % F_FULL;
    int s = idx / (HDIM * F_FULL);
    int drop = 4 * KK + s;  // 64+s
    float val = 0.0f;
    if (g != drop) {
        int src = g - (g > drop ? 1 : 0);
        val = W1[src * HDIM + h];
    }
    W1v[idx] = val;
}

// Transpose z (B,K,H,W) int32 -> zt u8 (H,W,B,K).
// Viewed as 4096x4096 matrix: In[r=b*16+k][c=h*64+w] -> Out[c][r].
__global__ __launch_bounds__(256) void transpose_kernel(const int* __restrict__ z,
                                                        uint8_t* __restrict__ zt) {
    __shared__ uint8_t tile[32][33];
    int t = threadIdx.x;
    int bx = blockIdx.x & 127;   // c tile
    int by = blockIdx.x >> 7;    // r tile
    int c0 = bx * 32, r0 = by * 32;
    int tx = t & 31, ty = t >> 5;        // ty 0..7
#pragma unroll
    for (int i = 0; i < 4; ++i) {
        int r = r0 + ty + 8 * i;
        tile[ty + 8 * i][tx] = (uint8_t)z[(size_t)r * 4096 + c0 + tx];
    }
    __syncthreads();
    int cy = t >> 3;     // 0..31
    int rg = t & 7;      // 0..7 -> 4 consecutive r each
    uchar4 v;
    v.x = tile[rg * 4 + 0][cy];
    v.y = tile[rg * 4 + 1][cy];
    v.z = tile[rg * 4 + 2][cy];
    v.w = tile[rg * 4 + 3][cy];
    *(uchar4*)(zt + (size_t)(c0 + cy) * 4096 + r0 + rg * 4) = v;
}

// Main fused kernel: one block = (n, 64-wide b tile).
__global__ __launch_bounds__(256) void main_kernel(
    const uint8_t* __restrict__ zt, const float* __restrict__ W1v,
    const float* __restrict__ b1, const float* __restrict__ W2,
    const float* __restrict__ b2, const int* __restrict__ z,
    const int* __restrict__ bs, const int* __restrict__ ii,
    const int* __restrict__ jj, int* __restrict__ err_count) {
    // smem: phase1 ctxT [144][64]; phase2 reuses as hL [64][132]; lg separate
    __shared__ float smem[F_FULL * 64 + 64 * CDIM];
    float* ctxT = smem;
    float* hL = smem;                 // 64*132 = 8448 <= 9216, safe reuse
    float* lg = smem + F_FULL * 64;   // [64][16]

    int t = threadIdx.x;
    int bid = blockIdx.x;
    int n = bid >> 2;
    int b_base = (bid & 3) << 6;

    int in_ = ii[n], jn = jj[n], sn = bs[n];

    // ---- stage ctxT[g][b] = z/15 for 9 neighbor pixels, 16 k, 64 b ----
    for (int item = t; item < 9 * 64; item += 256) {
        int p = item >> 6;
        int b = item & 63;
        int di = p / 3 - 1, dj = p % 3 - 1;
        int ni = (in_ + di + HH) & (HH - 1);
        int nj = (jn + dj + WW) & (WW - 1);
        const uint8_t* src = zt + (((size_t)(ni * WW + nj) * BB + (b_base + b)) << 4);
        uint4 raw = *(const uint4*)src;
        const uint8_t* bytes = (const uint8_t*)&raw;
#pragma unroll
        for (int k = 0; k < 16; ++k) {
            ctxT[(p * 16 + k) * 64 + b] = (float)bytes[k] * (1.0f / 15.0f);
        }
    }
    __syncthreads();

    // ---- GEMM1: (64 b) x (128 h) over K=144, micro-tile 4b x 8h ----
    int h0 = (t & 15) << 3;   // 0..120 step 8
    int b0 = (t >> 4) << 2;   // 0..60 step 4
    const float* w1 = W1v + (size_t)sn * (F_FULL * HDIM);

    float acc[4][8];
#pragma unroll
    for (int j = 0; j < 8; ++j) {
        float bv = b1[h0 + j];
        acc[0][j] = bv; acc[1][j] = bv; acc[2][j] = bv; acc[3][j] = bv;
    }
    for (int g = 0; g < F_FULL; ++g) {
        float4 cv = *(const float4*)(ctxT + g * 64 + b0);
        float4 wa = *(const float4*)(w1 + g * HDIM + h0);
        float4 wb = *(const float4*)(w1 + g * HDIM + h0 + 4);
        float c4[4] = {cv.x, cv.y, cv.z, cv.w};
        float w8[8] = {wa.x, wa.y, wa.z, wa.w, wb.x, wb.y, wb.z, wb.w};
#pragma unroll
        for (int i = 0; i < 4; ++i)
#pragma unroll
            for (int j = 0; j < 8; ++j)
                acc[i][j] = fmaf(c4[i], w8[j], acc[i][j]);
    }
    __syncthreads();   // all ctxT reads done before hL overwrite

    // ---- relu -> hL [64][132] (padded pitch) ----
#pragma unroll
    for (int i = 0; i < 4; ++i) {
        float4 v0 = make_float4(fmaxf(acc[i][0], 0.f), fmaxf(acc[i][1], 0.f),
                                fmaxf(acc[i][2], 0.f), fmaxf(acc[i][3], 0.f));
        float4 v1 = make_float4(fmaxf(acc[i][4], 0.f), fmaxf(acc[i][5], 0.f),
                                fmaxf(acc[i][6], 0.f), fmaxf(acc[i][7], 0.f));
        *(float4*)(hL + (b0 + i) * 132 + h0) = v0;
        *(float4*)(hL + (b0 + i) * 132 + h0 + 4) = v1;
    }
    __syncthreads();

    // ---- layer2: thread -> (b = t/4, 4 classes) ----
    int b = t >> 2;
    int c0 = (t & 3) << 2;
    float acc2[4] = {b2[c0], b2[c0 + 1], b2[c0 + 2], b2[c0 + 3]};
    for (int hh = 0; hh < HDIM; hh += 4) {
        float4 hv = *(const float4*)(hL + b * 132 + hh);
        float h4[4] = {hv.x, hv.y, hv.z, hv.w};
#pragma unroll
        for (int d = 0; d < 4; ++d) {
            float4 wv = *(const float4*)(W2 + (hh + d) * CDIM + c0);
            acc2[0] = fmaf(h4[d], wv.x, acc2[0]);
            acc2[1] = fmaf(h4[d], wv.y, acc2[1]);
            acc2[2] = fmaf(h4[d], wv.z, acc2[2]);
            acc2[3] = fmaf(h4[d], wv.w, acc2[3]);
        }
    }
    *(float4*)(lg + b * CDIM + c0) = make_float4(acc2[0], acc2[1], acc2[2], acc2[3]);
    __syncthreads();

    // ---- argmax + compare + ballot reduce (wave 0 only) ----
    if (t < 64) {
        float best = lg[t * CDIM];
        int pi = 0;
#pragma unroll
        for (int c = 1; c < CDIM; ++c) {
            float v = lg[t * CDIM + c];
            if (v > best) { best = v; pi = c; }   // strict > = first-max (jnp.argmax)
        }
        int bglob = b_base + t;
        int tgt = z[(((size_t)bglob * KK + sn) * HH + in_) * WW + jn];
        unsigned long long m = __ballot(pi != tgt);
        if (t == 0) atomicAdd(err_count, (int)__popcll(m));
    }
}

__global__ void finalize_kernel(const int* __restrict__ err_count, float* __restrict__ out) {
    out[0] = (float)(*err_count) / (float)(NB * BB);
}

extern "C" void kernel_launch(void* const* d_in, const int* in_sizes, int n_in,
                              void* d_out, int out_size, void* d_ws, size_t ws_size,
                              hipStream_t stream) {
    const int* z = (const int*)d_in[0];
    const int* bs = (const int*)d_in[1];
    const int* ii = (const int*)d_in[2];
    const int* jj = (const int*)d_in[3];
    const float* W1 = (const float*)d_in[4];
    const float* b1 = (const float*)d_in[5];
    const float* W2 = (const float*)d_in[6];
    const float* b2 = (const float*)d_in[7];
    float* out = (float*)d_out;

    uint8_t* ws = (uint8_t*)d_ws;
    int* err_count = (int*)ws;
    float* W1v = (float*)(ws + W1V_OFF);
    uint8_t* zt = ws + ZT_OFF;

    hipMemsetAsync(err_count, 0, sizeof(int), stream);
    build_w1v<<<(16 * F_FULL * HDIM + 255) / 256, 256, 0, stream>>>(W1, W1v);
    transpose_kernel<<<128 * 128, 256, 0, stream>>>(z, zt);
    main_kernel<<<NB * 4, 256, 0, stream>>>(zt, W1v, b1, W2, b2, z, bs, ii, jj, err_count);
    finalize_kernel<<<1, 1, 0, stream>>>(err_count, out);
}

// Round 2
// 169.872 us; speedup vs baseline: 1.7958x; 1.7958x over previous
//
#include <hip/hip_runtime.h>
#include <stdint.h>

#define NB 1024
#define BB 256
#define KK 16
#define HH 64
#define WW 64
#define F_FULL 144
#define HDIM 128
#define CDIM 16
#define KPAD 160
#define APITCH 168   // A LDS pitch (bf16 elems), 336 B rows: 16B-aligned, conflict-benign
#define HPITCH 136   // h LDS pitch (bf16 elems), 272 B rows: 16B-aligned

typedef __bf16 bf16x8 __attribute__((ext_vector_type(8)));
typedef float f32x4 __attribute__((ext_vector_type(4)));

// ---------------- ws layout ----------------
// [0,4)        : int err_count
// [256, ..)    : W1t bf16 [16][128][160]  (drop-shifted, h-major, k-contig, k>=144 zero)
// [.., ..)     : W2b bf16 [16][128]       (c-major, k-contig)
// [.., ..)     : zt u8 (H,W,B,K)
#define W1T_OFF 256
#define W1T_BYTES (16 * HDIM * KPAD * 2)
#define W2B_OFF (W1T_OFF + W1T_BYTES)
#define W2B_BYTES (CDIM * HDIM * 2)
#define ZT_OFF (W2B_OFF + W2B_BYTES)   // 659712, 256-aligned

__device__ __forceinline__ unsigned short bf16_bits(float v) {
    __bf16 b = (__bf16)v;
    return __builtin_bit_cast(unsigned short, b);
}

// W1t[s][h][k] = (k>=144 || k==64+s) ? 0 : bf16(W1[(k - (k > 64+s)) * 128 + h])
__global__ void build_w1t(const float* __restrict__ W1, unsigned short* __restrict__ W1t) {
    int idx = blockIdx.x * 256 + threadIdx.x;   // 16*128*160 = 327680
    if (idx >= 16 * HDIM * KPAD) return;
    int k = idx % KPAD;
    int h = (idx / KPAD) % HDIM;
    int s = idx / (KPAD * HDIM);
    int drop = 4 * KK + s;
    float val = 0.0f;
    if (k < F_FULL && k != drop) {
        int src = k - (k > drop ? 1 : 0);
        val = W1[src * HDIM + h];
    }
    W1t[idx] = bf16_bits(val);
}

// W2b[c][k] = bf16(W2[k*16 + c])
__global__ void build_w2b(const float* __restrict__ W2, unsigned short* __restrict__ W2b) {
    int idx = blockIdx.x * 256 + threadIdx.x;   // 16*128 = 2048
    if (idx >= CDIM * HDIM) return;
    int k = idx % HDIM;
    int c = idx / HDIM;
    W2b[idx] = bf16_bits(W2[k * CDIM + c]);
}

// Transpose z (B,K,H,W) int32 -> zt u8 (H,W,B,K).  (unchanged from round 1, verified)
__global__ __launch_bounds__(256) void transpose_kernel(const int* __restrict__ z,
                                                        uint8_t* __restrict__ zt) {
    __shared__ uint8_t tile[32][33];
    int t = threadIdx.x;
    int bx = blockIdx.x & 127;
    int by = blockIdx.x >> 7;
    int c0 = bx * 32, r0 = by * 32;
    int tx = t & 31, ty = t >> 5;
#pragma unroll
    for (int i = 0; i < 4; ++i) {
        int r = r0 + ty + 8 * i;
        tile[ty + 8 * i][tx] = (uint8_t)z[(size_t)r * 4096 + c0 + tx];
    }
    __syncthreads();
    int cy = t >> 3;
    int rg = t & 7;
    uchar4 v;
    v.x = tile[rg * 4 + 0][cy];
    v.y = tile[rg * 4 + 1][cy];
    v.z = tile[rg * 4 + 2][cy];
    v.w = tile[rg * 4 + 3][cy];
    *(uchar4*)(zt + (size_t)(c0 + cy) * 4096 + r0 + rg * 4) = v;
}

// Main fused MFMA kernel: one block = (n, 64-wide b tile), 4 waves.
__global__ __launch_bounds__(256, 3) void main_kernel(
    const uint8_t* __restrict__ zt, const unsigned short* __restrict__ W1t,
    const float* __restrict__ b1, const unsigned short* __restrict__ W2b,
    const float* __restrict__ b2, const int* __restrict__ bs,
    const int* __restrict__ ii, const int* __restrict__ jj,
    int* __restrict__ err_count) {
    __shared__ unsigned short sA[64 * APITCH];   // 21504 B  ctx bf16 [b][k]
    __shared__ unsigned short sH[64 * HPITCH];   // 17408 B  hidden bf16 [b][h]
    __shared__ float slg[64 * 17];               // 4352 B   logits fp32 [b][c]

    int t = threadIdx.x;
    int bid = blockIdx.x;
    int n = bid >> 2;
    int b_base = (bid & 3) << 6;
    int wave = t >> 6, lane = t & 63;
    int l15 = lane & 15, l4 = lane >> 4;

    int in_ = ii[n], jn = jj[n], sn = bs[n];

    // ---- zero A pad region k in [144,168) ----
    if (t < 192) {
        int b = t / 3, part = t % 3;
        *(uint4*)(sA + b * APITCH + F_FULL + part * 8) = make_uint4(0, 0, 0, 0);
    }

    // ---- B fragments (registers, global loads — L2-hot) ----
    const unsigned short* w1s = W1t + (size_t)sn * (HDIM * KPAD);
    int n0 = wave * 32;
    bf16x8 Bf[2][5];
#pragma unroll
    for (int nt = 0; nt < 2; ++nt)
#pragma unroll
        for (int ks = 0; ks < 5; ++ks)
            Bf[nt][ks] = *(const bf16x8*)(w1s + (n0 + nt * 16 + l15) * KPAD + ks * 32 + l4 * 8);
    bf16x8 Bf2[4];
#pragma unroll
    for (int ks = 0; ks < 4; ++ks)
        Bf2[ks] = *(const bf16x8*)(W2b + l15 * HDIM + ks * 32 + l4 * 8);
    float b1v0 = b1[n0 + l15], b1v1 = b1[n0 + 16 + l15];
    float b2v = b2[l15];

    // ---- stage ctx -> sA bf16: 9 pixels x 64 b x 16 k ----
    for (int item = t; item < 9 * 64; item += 256) {
        int p = item >> 6;
        int b = item & 63;
        int di = p / 3 - 1, dj = p % 3 - 1;
        int ni = (in_ + di + HH) & (HH - 1);
        int nj = (jn + dj + WW) & (WW - 1);
        const uint8_t* src = zt + (((size_t)(ni * WW + nj) * BB + (b_base + b)) << 4);
        uint4 raw = *(const uint4*)src;
        const uint8_t* bytes = (const uint8_t*)&raw;
        union { __bf16 h[16]; uint4 q[2]; } u;
#pragma unroll
        for (int k = 0; k < 16; ++k)
            u.h[k] = (__bf16)((float)bytes[k] * (1.0f / 15.0f));
        uint4* dst = (uint4*)(sA + b * APITCH + p * 16);
        dst[0] = u.q[0];
        dst[1] = u.q[1];
    }
    __syncthreads();

    // ---- GEMM1: M=64 x N=128 x K=160, wave owns 32 N-cols, 4 M-tiles ----
    f32x4 acc[4][2] = {};
#pragma unroll
    for (int mt = 0; mt < 4; ++mt) {
        bf16x8 Af[5];
#pragma unroll
        for (int ks = 0; ks < 5; ++ks)
            Af[ks] = *(const bf16x8*)(sA + (mt * 16 + l15) * APITCH + ks * 32 + l4 * 8);
#pragma unroll
        for (int ks = 0; ks < 5; ++ks) {
            acc[mt][0] = __builtin_amdgcn_mfma_f32_16x16x32_bf16(Af[ks], Bf[0][ks], acc[mt][0], 0, 0, 0);
            acc[mt][1] = __builtin_amdgcn_mfma_f32_16x16x32_bf16(Af[ks], Bf[1][ks], acc[mt][1], 0, 0, 0);
        }
    }

    // ---- bias + relu -> sH bf16 [b][h] ----
#pragma unroll
    for (int mt = 0; mt < 4; ++mt)
#pragma unroll
        for (int nt = 0; nt < 2; ++nt) {
            float bv = nt ? b1v1 : b1v0;
            int hcol = n0 + nt * 16 + l15;
#pragma unroll
            for (int r = 0; r < 4; ++r) {
                int b = mt * 16 + l4 * 4 + r;
                float v = fmaxf(acc[mt][nt][r] + bv, 0.0f);
                sH[b * HPITCH + hcol] = bf16_bits(v);
            }
        }
    __syncthreads();

    // ---- GEMM2: M=64 x N=16 x K=128; wave owns M-tile `wave` ----
    f32x4 acc2 = {};
#pragma unroll
    for (int ks = 0; ks < 4; ++ks) {
        bf16x8 Af = *(const bf16x8*)(sH + (wave * 16 + l15) * HPITCH + ks * 32 + l4 * 8);
        acc2 = __builtin_amdgcn_mfma_f32_16x16x32_bf16(Af, Bf2[ks], acc2, 0, 0, 0);
    }
#pragma unroll
    for (int r = 0; r < 4; ++r) {
        int b = wave * 16 + l4 * 4 + r;
        slg[b * 17 + l15] = acc2[r] + b2v;
    }
    __syncthreads();

    // ---- argmax + compare + ballot (wave 0) ----
    if (t < 64) {
        float best = slg[t * 17];
        int pi = 0;
#pragma unroll
        for (int c = 1; c < CDIM; ++c) {
            float v = slg[t * 17 + c];
            if (v > best) { best = v; pi = c; }   // strict > = first-max (jnp.argmax)
        }
        int tgt = zt[(((size_t)(in_ * WW + jn) * BB + b_base + t) << 4) + sn];
        unsigned long long m = __ballot(pi != tgt);
        if (t == 0) atomicAdd(err_count, (int)__popcll(m));
    }
}

__global__ void finalize_kernel(const int* __restrict__ err_count, float* __restrict__ out) {
    out[0] = (float)(*err_count) / (float)(NB * BB);
}

extern "C" void kernel_launch(void* const* d_in, const int* in_sizes, int n_in,
                              void* d_out, int out_size, void* d_ws, size_t ws_size,
                              hipStream_t stream) {
    const int* z = (const int*)d_in[0];
    const int* bs = (const int*)d_in[1];
    const int* ii = (const int*)d_in[2];
    const int* jj = (const int*)d_in[3];
    const float* W1 = (const float*)d_in[4];
    const float* b1 = (const float*)d_in[5];
    const float* W2 = (const float*)d_in[6];
    const float* b2 = (const float*)d_in[7];
    float* out = (float*)d_out;

    uint8_t* ws = (uint8_t*)d_ws;
    int* err_count = (int*)ws;
    unsigned short* W1t = (unsigned short*)(ws + W1T_OFF);
    unsigned short* W2b = (unsigned short*)(ws + W2B_OFF);
    uint8_t* zt = ws + ZT_OFF;

    hipMemsetAsync(err_count, 0, sizeof(int), stream);
    build_w1t<<<(16 * HDIM * KPAD + 255) / 256, 256, 0, stream>>>(W1, W1t);
    build_w2b<<<(CDIM * HDIM + 255) / 256, 256, 0, stream>>>(W2, W2b);
    transpose_kernel<<<128 * 128, 256, 0, stream>>>(z, zt);
    main_kernel<<<NB * 4, 256, 0, stream>>>(zt, W1t, b1, W2b, b2, bs, ii, jj, err_count);
    finalize_kernel<<<1, 1, 0, stream>>>(err_count, out);
}